// Round 1
// baseline (288.122 us; speedup 1.0000x reference)
//
#include <hip/hip_runtime.h>

// Output = conv1x1(x, refine_w, refine_b). Everything else in the reference is
// dead code: `_dead` is unused, and x_back == x exactly (permutation followed
// by its argsort-inverse).
//
// x: (8, 64, 256, 256) fp32, refine_w: (64, 64) [o-major], refine_b: (64,)
// out[b,o,h,w] = sum_c w[o,c] * x[b,c,h,w] + b[o]

constexpr int  C    = 64;
constexpr long HW   = 65536;      // 256*256
constexpr long NPIX = 8L * HW;    // 524288 pixels total
constexpr int  P    = 2;          // pixels per thread (float2 loads/stores)

__global__ __launch_bounds__(256, 2) void conv1x1_refine_kernel(
    const float* __restrict__ x,
    const float* __restrict__ w,     // (64,64) o-major
    const float* __restrict__ bias,  // (64,)
    float* __restrict__ out)
{
    const long tid = (long)blockIdx.x * blockDim.x + threadIdx.x;
    const long pix = tid * P;              // first pixel of this thread's pair
    const long b   = pix >> 16;            // pix / HW
    const long hw  = pix & (HW - 1);       // pix % HW

    const float* xb = x   + b * (C * HW) + hw;
    float*       ob = out + b * (C * HW) + hw;

    float2 acc[C];
#pragma unroll
    for (int o = 0; o < C; ++o) {
        const float bv = bias[o];          // uniform -> s_load
        acc[o].x = bv;
        acc[o].y = bv;
    }

#pragma unroll 2
    for (int c = 0; c < C; ++c) {
        const float2 xv = *reinterpret_cast<const float2*>(xb + (long)c * HW);
#pragma unroll
        for (int o = 0; o < C; ++o) {
            const float wv = w[o * C + c]; // uniform address -> s_load (SGPR operand of v_fma)
            acc[o].x = fmaf(wv, xv.x, acc[o].x);
            acc[o].y = fmaf(wv, xv.y, acc[o].y);
        }
    }

#pragma unroll
    for (int o = 0; o < C; ++o) {
        *reinterpret_cast<float2*>(ob + (long)o * HW) = acc[o];
    }
}

extern "C" void kernel_launch(void* const* d_in, const int* in_sizes, int n_in,
                              void* d_out, int out_size, void* d_ws, size_t ws_size,
                              hipStream_t stream)
{
    const float* x  = (const float*)d_in[0];   // x
    const float* rw = (const float*)d_in[11];  // refine_w
    const float* rb = (const float*)d_in[12];  // refine_b
    float* out = (float*)d_out;

    const int threads = 256;
    const int blocks  = (int)(NPIX / P / threads);  // 1024
    hipLaunchKernelGGL(conv1x1_refine_kernel, dim3(blocks), dim3(threads), 0, stream,
                       x, rw, rb, out);
}